// Round 10
// baseline (101.634 us; speedup 1.0000x reference)
//
#include <hip/hip_runtime.h>
#include <math.h>

#define EMB 512
#define NM 5
#define HID 64
#define NQ 2048
#define NP 256
#define NROWS 2304            // NQ + NP
#define NRT 144               // row-tiles of 16
#define NC 16                 // K-chunks of 32 (K=512)

typedef __attribute__((ext_vector_type(8))) short short8;   // 8 bf16 = 4 VGPR
typedef __attribute__((ext_vector_type(4))) float floatx4;

// ws layout (bytes)
#define A_BY      0u          // A[m][q][h] f32 (+b1)          2,621,440
#define B_BY      2621440u    // B[m][h/4][p][h%4] f32           327,680
#define PXH_BY    2949120u    // X-frag hi: [rt*16+c][lane][8] 2,359,296
#define PXL_BY    5308416u    // X-frag lo                     2,359,296
#define PWH_BY    7667712u    // W-frag hi: [((m*2+half)*4+ht)*16+c][lane][8] 655,360
#define PWL_BY    8323072u

__device__ inline unsigned short bfr(float f) {            // f32 -> bf16 RNE
    unsigned u = __float_as_uint(f);
    u += 0x7FFFu + ((u >> 16) & 1u);
    return (unsigned short)(u >> 16);
}

// ---------------------------------------------------------------------------
// Kernel 1: convert Q/P/W1 -> hi/lo bf16, pre-swizzled into MFMA fragment
// order so gemm_pk reads are perfectly coalesced 16B/lane.
// Wave ids: 0..2303 = X tiles (rt, c); 2304..2943 = W tiles (m, half, ht, c).
// Fragment: lane&15 -> row/h, (lane>>4)*8 -> k offset within 32-chunk.
__global__ __launch_bounds__(256) void conv_pack(const float* __restrict__ Q,
                                                 const float* __restrict__ P,
                                                 const float* __restrict__ W1,
                                                 char* __restrict__ ws) {
    short* PXH = (short*)(ws + PXH_BY);
    short* PXL = (short*)(ws + PXL_BY);
    short* PWH = (short*)(ws + PWH_BY);
    short* PWL = (short*)(ws + PWL_BY);

    int lane = threadIdx.x & 63;
    int wid  = blockIdx.x * 4 + (threadIdx.x >> 6);
    int kq   = (lane >> 4) * 8;

    const float* src;
    short *dh, *dl;
    if (wid < NRT * NC) {
        int rt = wid >> 4, c = wid & 15;
        int r  = rt * 16 + (lane & 15);
        src = (r < NQ ? Q + (size_t)r * EMB : P + (size_t)(r - NQ) * EMB)
              + c * 32 + kq;
        dh = PXH + (size_t)wid * 512 + lane * 8;
        dl = PXL + (size_t)wid * 512 + lane * 8;
    } else {
        int u = wid - NRT * NC;          // ((m*2+half)*4+ht)*16+c
        int c = u & 15, ht = (u >> 4) & 3, half = (u >> 6) & 1, m = u >> 7;
        int h = ht * 16 + (lane & 15);
        src = W1 + ((size_t)m * 64 + h) * 1024 + half * EMB + c * 32 + kq;
        dh = PWH + (size_t)u * 512 + lane * 8;
        dl = PWL + (size_t)u * 512 + lane * 8;
    }

    float4 v0 = *(const float4*)&src[0];
    float4 v1 = *(const float4*)&src[4];
    short8 hh, ll;
#define CNV(I, VAL) { unsigned short h_ = bfr(VAL); hh[I] = (short)h_; \
    float hf_ = __uint_as_float(((unsigned)h_) << 16); ll[I] = (short)bfr((VAL) - hf_); }
    CNV(0, v0.x) CNV(1, v0.y) CNV(2, v0.z) CNV(3, v0.w)
    CNV(4, v1.x) CNV(5, v1.y) CNV(6, v1.z) CNV(7, v1.w)
#undef CNV
    *(short8*)dh = hh;
    *(short8*)dl = ll;
}

// ---------------------------------------------------------------------------
// Kernel 2: barrier-free MFMA GEMM. Block = (m, rt); wave = 16x16 h-tile ht.
// All fragment loads are coalesced 1KB wave-loads from the packed arrays.
// Split-bf16: hi*lo + lo*hi + hi*hi. Writes A(+b1) / blocked-B directly.
__global__ __launch_bounds__(256) void gemm_pk(const char* __restrict__ ws_ro,
                                               const float* __restrict__ b1,
                                               float* __restrict__ A,
                                               float* __restrict__ Bv) {
    const short* PXH = (const short*)(ws_ro + PXH_BY);
    const short* PXL = (const short*)(ws_ro + PXL_BY);
    const short* PWH = (const short*)(ws_ro + PWH_BY);
    const short* PWL = (const short*)(ws_ro + PWL_BY);

    int lane = threadIdx.x & 63;
    int ht   = threadIdx.x >> 6;
    int m    = blockIdx.x % 5;
    int rt   = blockIdx.x / 5;           // 0..143
    bool isQ = rt < 128;
    int half = isQ ? 0 : 1;

    const short* ax = PXH + ((size_t)rt * 16) * 512 + lane * 8;
    const short* al = PXL + ((size_t)rt * 16) * 512 + lane * 8;
    size_t wbase = ((size_t)((m * 2 + half) * 4 + ht) * 16) * 512 + lane * 8;
    const short* bh = PWH + wbase;
    const short* bl = PWL + wbase;

    floatx4 ac = {0, 0, 0, 0};
#pragma unroll 4
    for (int c = 0; c < NC; ++c) {
        short8 Ah = *(const short8*)&ax[c * 512];
        short8 Al = *(const short8*)&al[c * 512];
        short8 Bh = *(const short8*)&bh[c * 512];
        short8 Bl = *(const short8*)&bl[c * 512];
        ac = __builtin_amdgcn_mfma_f32_16x16x32_bf16(Ah, Bl, ac, 0, 0, 0);
        ac = __builtin_amdgcn_mfma_f32_16x16x32_bf16(Al, Bh, ac, 0, 0, 0);
        ac = __builtin_amdgcn_mfma_f32_16x16x32_bf16(Ah, Bh, ac, 0, 0, 0);
    }

    int col  = lane & 15;                 // h within tile
    int rloc = (lane >> 4) * 4;           // row within tile (+reg)
    int h    = ht * 16 + col;
    int r    = rt * 16 + rloc;

    if (isQ) {
        float bb = b1[m * 64 + h];
        float* dst = &A[((size_t)m * NQ + r) * HID + h];
        dst[0 * HID] = ac.x + bb; dst[1 * HID] = ac.y + bb;
        dst[2 * HID] = ac.z + bb; dst[3 * HID] = ac.w + bb;
    } else {
        int p = r - NQ;
        float* dst = &Bv[(((size_t)(m * 16 + (h >> 2))) * NP + p) * 4 + (h & 3)];
        dst[0 * 4] = ac.x; dst[1 * 4] = ac.y; dst[2 * 4] = ac.z; dst[3 * 4] = ac.w;
    }
}

// ---------------------------------------------------------------------------
// Kernel 3: fused relu-ensemble + mean/std/exp. 4 q per thread (512 blocks)
// halves the per-output B re-read traffic vs 2 q. Named regs only.
__global__ __launch_bounds__(256) void fused_main(const float* __restrict__ A,
                                                  const float* __restrict__ Bv,
                                                  const float* __restrict__ W2,
                                                  const float* __restrict__ b2,
                                                  float* __restrict__ out) {
    int p  = threadIdx.x;            // 0..255
    int q0 = blockIdx.x * 4;

    float s10 = 0, s20 = 0, s11 = 0, s21 = 0;
    float s12 = 0, s22 = 0, s13 = 0, s23 = 0;
    const float4* Bq = (const float4*)Bv + p;

#pragma unroll 1
    for (int m = 0; m < NM; ++m) {
        const float4* bm = Bq + (size_t)m * 16 * NP;
        float4 B0 = bm[0*NP],  B1 = bm[1*NP],  B2 = bm[2*NP],  B3 = bm[3*NP];
        float4 B4 = bm[4*NP],  B5 = bm[5*NP],  B6 = bm[6*NP],  B7 = bm[7*NP];
        float4 B8 = bm[8*NP],  B9 = bm[9*NP],  B10= bm[10*NP], B11= bm[11*NP];
        float4 B12= bm[12*NP], B13= bm[13*NP], B14= bm[14*NP], B15= bm[15*NP];

        const float* Ar  = A + ((size_t)m * NQ + q0) * HID;   // block-uniform
        const float* Wp2 = W2 + m * HID;                      // block-uniform
        float o0 = 0.f, o1 = 0.f, o2 = 0.f, o3 = 0.f;

#define HS1(OA, QO, BF, H0, WA, WB, WC, WD) \
        OA = fmaf(fmaxf(Ar[QO*HID+H0+0] + BF.x, 0.f), WA, OA); \
        OA = fmaf(fmaxf(Ar[QO*HID+H0+1] + BF.y, 0.f), WB, OA); \
        OA = fmaf(fmaxf(Ar[QO*HID+H0+2] + BF.z, 0.f), WC, OA); \
        OA = fmaf(fmaxf(Ar[QO*HID+H0+3] + BF.w, 0.f), WD, OA);
#define HSTEP(BF, H0) { \
        float wa=Wp2[H0+0], wb=Wp2[H0+1], wc=Wp2[H0+2], wd=Wp2[H0+3]; \
        HS1(o0, 0, BF, H0, wa, wb, wc, wd) \
        HS1(o1, 1, BF, H0, wa, wb, wc, wd) \
        HS1(o2, 2, BF, H0, wa, wb, wc, wd) \
        HS1(o3, 3, BF, H0, wa, wb, wc, wd) }

        HSTEP(B0,  0)  HSTEP(B1,  4)  HSTEP(B2,  8)  HSTEP(B3, 12)
        HSTEP(B4, 16)  HSTEP(B5, 20)  HSTEP(B6, 24)  HSTEP(B7, 28)
        HSTEP(B8, 32)  HSTEP(B9, 36)  HSTEP(B10,40)  HSTEP(B11,44)
        HSTEP(B12,48)  HSTEP(B13,52)  HSTEP(B14,56)  HSTEP(B15,60)
#undef HSTEP
#undef HS1

        float bb = b2[m];
        float x0 = o0 + bb, x1 = o1 + bb, x2 = o2 + bb, x3 = o3 + bb;
        s10 += x0; s20 = fmaf(x0, x0, s20);
        s11 += x1; s21 = fmaf(x1, x1, s21);
        s12 += x2; s22 = fmaf(x2, x2, s22);
        s13 += x3; s23 = fmaf(x3, x3, s23);
    }

#define OUTW(J, S1, S2) { \
        float mean = S1 * 0.2f; \
        float var  = fmaxf((S2 - S1 * S1 * 0.2f) * 0.25f, 0.f); \
        out[(size_t)(q0 + J) * NP + p] = mean * __expf(-sqrtf(var)); }
    OUTW(0, s10, s20) OUTW(1, s11, s21) OUTW(2, s12, s22) OUTW(3, s13, s23)
#undef OUTW
}

// ---------------------------------------------------------------------------
extern "C" void kernel_launch(void* const* d_in, const int* in_sizes, int n_in,
                              void* d_out, int out_size, void* d_ws, size_t ws_size,
                              hipStream_t stream) {
    const float* Q  = (const float*)d_in[0];   // (2048, 512)
    const float* P  = (const float*)d_in[1];   // (256, 512)
    const float* W1 = (const float*)d_in[2];   // (5, 64, 1024)
    const float* b1 = (const float*)d_in[3];   // (5, 64)
    const float* W2 = (const float*)d_in[4];   // (5, 64)
    const float* b2 = (const float*)d_in[5];   // (5,)
    float* out = (float*)d_out;

    char*  ws = (char*)d_ws;
    float* A  = (float*)(ws + A_BY);
    float* B  = (float*)(ws + B_BY);

    conv_pack<<<736, 256, 0, stream>>>(Q, P, W1, ws);
    gemm_pk<<<720, 256, 0, stream>>>(ws, b1, A, B);
    fused_main<<<NQ / 4, 256, 0, stream>>>(A, B, W2, b2, out);
}